// Round 14
// baseline (3289.532 us; speedup 1.0000x reference)
//
#include <hip/hip_runtime.h>
#include <hip/hip_bf16.h>
#include <stdint.h>

#define S_LEN 4096
#define HN    32
#define SSD   64
#define KD    2048      // D_IN = H*SS = D_OUT
#define MROWS 16384     // B*S

typedef __attribute__((ext_vector_type(4))) float f32x4;
typedef __attribute__((ext_vector_type(8))) short bf16x8;
typedef __attribute__((ext_vector_type(2))) int i32x2;
typedef __attribute__((ext_vector_type(2))) _Float16 f16x2;
typedef __attribute__((address_space(3))) char as3char;
typedef __attribute__((address_space(1))) char as1char;

__device__ __forceinline__ unsigned short f2bf(float f){
  unsigned int u = __float_as_uint(f);
  u += 0x7FFFu + ((u >> 16) & 1u);   // round-to-nearest-even
  return (unsigned short)(u >> 16);
}

__device__ __forceinline__ f16x2 bc_h2(int v){
  union { int i; f16x2 h; } u; u.i = v; return u.h;
}

// pack own y (f16) with DPP quad_perm[1,0,3,2] neighbor -> pair reg.
// Only even lanes' packs are consumed by readlane(2k) -> order correct.
__device__ __forceinline__ int packpair(float y){
  const unsigned hb = (unsigned)__builtin_bit_cast(unsigned short, (_Float16)y);
  const int nb = __builtin_amdgcn_update_dpp(0, (int)hb, 0xB1, 0xF, 0xF, true);
  return (int)(hb | ((unsigned)nb << 16));
}

// ---------------- convert f32 -> bf16 (vectorized, 4 elts/thread) ----------------
__global__ __launch_bounds__(256) void cvt_bf16_k(const float* __restrict__ src,
                                                  unsigned short* __restrict__ dst){
  int i = (blockIdx.x * 256 + threadIdx.x) * 4;
  float4 v = *(const float4*)(src + i);
  ushort4 r;
  r.x = f2bf(v.x); r.y = f2bf(v.y); r.z = f2bf(v.z); r.w = f2bf(v.w);
  *(ushort4*)(dst + i) = r;
}

// ---------------- GEMM (bf16, global_load_lds), optional bias epilogue ----------------
__global__ __launch_bounds__(256) void gemm_bf16_k(const unsigned short* __restrict__ A,
                                                   const unsigned short* __restrict__ Bw,
                                                   const float* __restrict__ bias,  // may be null
                                                   float* __restrict__ C){
  __shared__ short As[128*32];
  __shared__ short Bs[128*32];
  const int tid  = threadIdx.x;
  const int bn   = blockIdx.x & 15;
  const int bm   = blockIdx.x >> 4;
  const int lane = tid & 63;
  const int wv   = tid >> 6;
  const int wvU  = __builtin_amdgcn_readfirstlane(wv);
  const int wm   = (wv >> 1) * 64;
  const int wn   = (wv & 1) * 64;

  f32x4 acc[4][4];
#pragma unroll
  for (int i=0;i<4;i++)
#pragma unroll
    for (int j=0;j<4;j++)
#pragma unroll
      for (int q=0;q<4;q++) acc[i][j][q] = 0.0f;

  as3char* asB = (as3char*)As;
  as3char* bsB = (as3char*)Bs;
  as1char* aG  = (as1char*)A;
  as1char* bG  = (as1char*)Bw;

  const int fr  = lane & 15;
  const int fko = (lane >> 4) * 8;

  for (int kt=0; kt<KD/32; ++kt){
    __syncthreads();                 // previous tile's frag reads done
#pragma unroll
    for (int c=0;c<2;c++){
      const int off  = (wvU*2 + c)*1024 + lane*16;
      const int row  = off >> 6;
      const int colB = off & 63;
      __builtin_amdgcn_global_load_lds(
        (__attribute__((address_space(1))) void*)(aG + (size_t)(bm*128 + row)*4096 + (size_t)kt*64 + colB),
        (__attribute__((address_space(3))) void*)(asB + (wvU*2 + c)*1024),
        16, 0, 0);
      __builtin_amdgcn_global_load_lds(
        (__attribute__((address_space(1))) void*)(bG + (size_t)(bn*128 + row)*4096 + (size_t)kt*64 + colB),
        (__attribute__((address_space(3))) void*)(bsB + (wvU*2 + c)*1024),
        16, 0, 0);
    }
    __syncthreads();                 // loads landed (vmcnt drain at barrier)

    bf16x8 af[4], bq[4];
#pragma unroll
    for (int mt=0; mt<4; mt++) af[mt] = *(const bf16x8*)&As[(wm + mt*16 + fr)*32 + fko];
#pragma unroll
    for (int nt=0; nt<4; nt++) bq[nt] = *(const bf16x8*)&Bs[(wn + nt*16 + fr)*32 + fko];
#pragma unroll
    for (int mt=0; mt<4; mt++)
#pragma unroll
      for (int nt=0; nt<4; nt++)
        acc[mt][nt] = __builtin_amdgcn_mfma_f32_16x16x32_bf16(af[mt], bq[nt], acc[mt][nt], 0, 0, 0);
  }

  float bv[4] = {0.f, 0.f, 0.f, 0.f};
  if (bias){
#pragma unroll
    for (int nt=0; nt<4; nt++) bv[nt] = bias[bn*128 + wn + nt*16 + fr];
  }
#pragma unroll
  for (int mt=0; mt<4; mt++)
#pragma unroll
    for (int nt=0; nt<4; nt++){
      const int col = bn*128 + wn + nt*16 + fr;
#pragma unroll
      for (int q=0; q<4; q++){
        const int row = bm*128 + wm + mt*16 + (lane>>4)*4 + q;
        C[(size_t)row*KD + col] = acc[mt][nt][q] + bv[nt];
      }
    }
}

// ---------------- scan: y_t = tanh(W_h y_{t-1} + hx_t) ----------------
// FOUR chains (all batches of head h) per wave, sharing ONE set of packed
// f16x2 weights. R12 established: step = ~490cyc = ~300 issue + ~190 dep-
// stall (dot/tanh/pack chains). Four independent chains interleave their
// issue into each other's stalls -> effective per-chain-step ~300 cyc.
// Core per chain: 32 readlane + 32 v_dot2_f32_f16 (R12 numbers:
// readlane ~5.5cyc, dot2 ~2cyc). grid = 32 blocks (one per head).
__global__ __attribute__((amdgpu_flat_work_group_size(64, 64)))
__attribute__((amdgpu_waves_per_eu(1, 1)))
void scan_k(const float* __restrict__ hx,
            const float* __restrict__ sw,   // [32][64][64]
            const float* __restrict__ st0,  // [4][32][64]
            unsigned short* __restrict__ ybf){ // [MROWS][2048] bf16
  const int h = blockIdx.x;            // head
  const int lane = threadIdx.x;        // = output index o
  const f32x4* wv = (const f32x4*)(sw + ((size_t)(h*64 + lane))*64);

  // pack W row into 32 named f16x2 (pairs (2k,2k+1)) -- shared by 4 chains
#define MKP(Q, PA, PB) { f32x4 q_ = wv[Q]; \
    PA = f16x2{(_Float16)q_[0], (_Float16)q_[1]}; \
    PB = f16x2{(_Float16)q_[2], (_Float16)q_[3]}; }
  f16x2 p0,p1,p2,p3,p4,p5,p6,p7,p8,p9,p10,p11,p12,p13,p14,p15,
        p16,p17,p18,p19,p20,p21,p22,p23,p24,p25,p26,p27,p28,p29,p30,p31;
  MKP(0,p0,p1)   MKP(1,p2,p3)   MKP(2,p4,p5)   MKP(3,p6,p7)
  MKP(4,p8,p9)   MKP(5,p10,p11) MKP(6,p12,p13) MKP(7,p14,p15)
  MKP(8,p16,p17) MKP(9,p18,p19) MKP(10,p20,p21)MKP(11,p22,p23)
  MKP(12,p24,p25)MKP(13,p26,p27)MKP(14,p28,p29)MKP(15,p30,p31)
#undef MKP
  asm volatile("" : "+v"(p0),"+v"(p1),"+v"(p2),"+v"(p3),"+v"(p4),"+v"(p5),
                    "+v"(p6),"+v"(p7),"+v"(p8),"+v"(p9),"+v"(p10),"+v"(p11),
                    "+v"(p12),"+v"(p13),"+v"(p14),"+v"(p15));
  asm volatile("" : "+v"(p16),"+v"(p17),"+v"(p18),"+v"(p19),"+v"(p20),"+v"(p21),
                    "+v"(p22),"+v"(p23),"+v"(p24),"+v"(p25),"+v"(p26),"+v"(p27),
                    "+v"(p28),"+v"(p29),"+v"(p30),"+v"(p31));

  __shared__ __align__(16) unsigned short ybuf[4][4][64];   // 2KB staging

  float yA = st0[(0*32 + h)*64 + lane];
  float yB = st0[(1*32 + h)*64 + lane];
  float yC = st0[(2*32 + h)*64 + lane];
  float yD = st0[(3*32 + h)*64 + lane];
  int ypA = packpair(yA), ypB = packpair(yB), ypC = packpair(yC), ypD = packpair(yD);

  const float* hxpA = hx + (size_t)0*S_LEN*KD + h*64 + lane;
  const float* hxpB = hx + (size_t)1*S_LEN*KD + h*64 + lane;
  const float* hxpC = hx + (size_t)2*S_LEN*KD + h*64 + lane;
  const float* hxpD = hx + (size_t)3*S_LEN*KD + h*64 + lane;
  unsigned short* const ybA = ybf + (size_t)0*S_LEN*KD + h*64;
  unsigned short* const ybB = ybf + (size_t)1*S_LEN*KD + h*64;
  unsigned short* const ybC = ybf + (size_t)2*S_LEN*KD + h*64;
  unsigned short* const ybD = ybf + (size_t)3*S_LEN*KD + h*64;
  const int srow = lane >> 4;          // drain: buffered row (0..3)
  const int scol = (lane & 15) << 2;   // drain: 4-ushort (8B) chunk in row

  // named prefetch registers: depth 4 per chain
  float hA0=hxpA[0*(size_t)KD], hA1=hxpA[1*(size_t)KD], hA2=hxpA[2*(size_t)KD], hA3=hxpA[3*(size_t)KD];
  float hB0=hxpB[0*(size_t)KD], hB1=hxpB[1*(size_t)KD], hB2=hxpB[2*(size_t)KD], hB3=hxpB[3*(size_t)KD];
  float hC0=hxpC[0*(size_t)KD], hC1=hxpC[1*(size_t)KD], hC2=hxpC[2*(size_t)KD], hC3=hxpC[3*(size_t)KD];
  float hD0=hxpD[0*(size_t)KD], hD1=hxpD[1*(size_t)KD], hD2=hxpD[2*(size_t)KD], hD3=hxpD[3*(size_t)KD];

// 8 readlanes for one chain in group G (even lanes -> pairs)
#define RL8(C, G) \
    const int t##C##0=__builtin_amdgcn_readlane(yp##C,(G)*16+ 0); \
    const int t##C##1=__builtin_amdgcn_readlane(yp##C,(G)*16+ 2); \
    const int t##C##2=__builtin_amdgcn_readlane(yp##C,(G)*16+ 4); \
    const int t##C##3=__builtin_amdgcn_readlane(yp##C,(G)*16+ 6); \
    const int t##C##4=__builtin_amdgcn_readlane(yp##C,(G)*16+ 8); \
    const int t##C##5=__builtin_amdgcn_readlane(yp##C,(G)*16+10); \
    const int t##C##6=__builtin_amdgcn_readlane(yp##C,(G)*16+12); \
    const int t##C##7=__builtin_amdgcn_readlane(yp##C,(G)*16+14);

#define DT8(C, P0,P1,P2,P3,P4,P5,P6,P7) \
    a##C##0=__builtin_amdgcn_fdot2(P0,bc_h2(t##C##0),a##C##0,false); \
    a##C##1=__builtin_amdgcn_fdot2(P1,bc_h2(t##C##1),a##C##1,false); \
    a##C##2=__builtin_amdgcn_fdot2(P2,bc_h2(t##C##2),a##C##2,false); \
    a##C##3=__builtin_amdgcn_fdot2(P3,bc_h2(t##C##3),a##C##3,false); \
    a##C##0=__builtin_amdgcn_fdot2(P4,bc_h2(t##C##4),a##C##0,false); \
    a##C##1=__builtin_amdgcn_fdot2(P5,bc_h2(t##C##5),a##C##1,false); \
    a##C##2=__builtin_amdgcn_fdot2(P6,bc_h2(t##C##6),a##C##2,false); \
    a##C##3=__builtin_amdgcn_fdot2(P7,bc_h2(t##C##7),a##C##3,false);

#define GRP(G, P0,P1,P2,P3,P4,P5,P6,P7) { \
    RL8(A, G) RL8(B, G) RL8(C, G) RL8(D, G) \
    __builtin_amdgcn_sched_barrier(0); \
    DT8(A, P0,P1,P2,P3,P4,P5,P6,P7) \
    DT8(B, P0,P1,P2,P3,P4,P5,P6,P7) \
    DT8(C, P0,P1,P2,P3,P4,P5,P6,P7) \
    DT8(D, P0,P1,P2,P3,P4,P5,P6,P7) \
    __builtin_amdgcn_sched_barrier(0); }

#define FIN(C, CI, XV, J) { \
    const float u = (a##C##0 + a##C##1) + (a##C##2 + a##C##3) + (XV); \
    const float e = __expf(2.0f*u); \
    y##C = 1.0f - 2.0f*__builtin_amdgcn_rcpf(e + 1.0f); \
    ybuf[CI][J][lane] = f2bf(y##C); \
    yp##C = packpair(y##C); }

#define STEP4(HA_,HB_,HC_,HD_, J, TT) { \
    const float xvA=HA_, xvB=HB_, xvC=HC_, xvD=HD_; \
    { const int tn_ = ((TT)+4 < S_LEN) ? ((TT)+4) : (S_LEN-1); \
      HA_ = hxpA[(size_t)tn_*KD]; HB_ = hxpB[(size_t)tn_*KD]; \
      HC_ = hxpC[(size_t)tn_*KD]; HD_ = hxpD[(size_t)tn_*KD]; } \
    float aA0=0.f,aA1=0.f,aA2=0.f,aA3=0.f, aB0=0.f,aB1=0.f,aB2=0.f,aB3=0.f; \
    float aC0=0.f,aC1=0.f,aC2=0.f,aC3=0.f, aD0=0.f,aD1=0.f,aD2=0.f,aD3=0.f; \
    GRP(0, p0,p1,p2,p3,p4,p5,p6,p7) \
    GRP(1, p8,p9,p10,p11,p12,p13,p14,p15) \
    GRP(2, p16,p17,p18,p19,p20,p21,p22,p23) \
    GRP(3, p24,p25,p26,p27,p28,p29,p30,p31) \
    FIN(A, 0, xvA, J) FIN(B, 1, xvB, J) FIN(C, 2, xvC, J) FIN(D, 3, xvD, J) }

  for (int t = 0; t < S_LEN; t += 4){
    STEP4(hA0,hB0,hC0,hD0, 0, t+0)
    STEP4(hA1,hB1,hC1,hD1, 1, t+1)
    STEP4(hA2,hB2,hC2,hD2, 2, t+2)
    STEP4(hA3,hB3,hC3,hD3, 3, t+3)
    // drain the 4-step tiles: one 8B store per lane per chain
    { const i32x2 v = *(const i32x2*)&ybuf[0][srow][scol];
      *(i32x2*)(ybA + (size_t)(t + srow)*KD + scol) = v; }
    { const i32x2 v = *(const i32x2*)&ybuf[1][srow][scol];
      *(i32x2*)(ybB + (size_t)(t + srow)*KD + scol) = v; }
    { const i32x2 v = *(const i32x2*)&ybuf[2][srow][scol];
      *(i32x2*)(ybC + (size_t)(t + srow)*KD + scol) = v; }
    { const i32x2 v = *(const i32x2*)&ybuf[3][srow][scol];
      *(i32x2*)(ybD + (size_t)(t + srow)*KD + scol) = v; }
  }
#undef STEP4
#undef FIN
#undef GRP
#undef DT8
#undef RL8
}

extern "C" void kernel_launch(void* const* d_in, const int* in_sizes, int n_in,
                              void* d_out, int out_size, void* d_ws, size_t ws_size,
                              hipStream_t stream) {
  const float* x      = (const float*)d_in[0];
  const float* st0    = (const float*)d_in[1];
  const float* w_in   = (const float*)d_in[2];
  const float* w_st   = (const float*)d_in[3];
  const float* b_st   = (const float*)d_in[4];
  const float* w_out  = (const float*)d_in[5];
  float* out = (float*)d_out;

  const size_t HX_B = (size_t)MROWS * KD * 4;       // 134217728
  const size_t Y_B  = (size_t)MROWS * KD * 2;       // 67108864
  const size_t WO_B = (size_t)KD * KD * 2;          // 8388608
  if (ws_size < HX_B + Y_B + WO_B) return;          // fail loudly rather than corrupt
  char* ws = (char*)d_ws;
  float*          hx   = (float*)ws;
  unsigned short* ybf  = (unsigned short*)(ws + HX_B);   // doubles as x_bf16
  unsigned short* wbf  = (unsigned short*)(ws + HX_B + Y_B); // w_in then w_out

  // phase 1: convert x and w_in, input GEMM (+bias)
  cvt_bf16_k<<<dim3((MROWS*(size_t)KD)/1024), dim3(256), 0, stream>>>(x, ybf);
  cvt_bf16_k<<<dim3((KD*KD)/1024), dim3(256), 0, stream>>>(w_in, wbf);
  gemm_bf16_k<<<dim3((MROWS/128)*(KD/128)), dim3(256), 0, stream>>>(ybf, wbf, b_st, hx);
  // phase 2: scan (overwrites x_bf16 region with y), then output GEMM
  scan_k<<<dim3(HN), dim3(64), 0, stream>>>(hx, w_st, st0, ybf);
  cvt_bf16_k<<<dim3((KD*KD)/1024), dim3(256), 0, stream>>>(w_out, wbf);
  gemm_bf16_k<<<dim3((MROWS/128)*(KD/128)), dim3(256), 0, stream>>>(ybf, wbf, nullptr, out);
}

// Round 15
// 1052.279 us; speedup vs baseline: 3.1261x; 3.1261x over previous
//
#include <hip/hip_runtime.h>
#include <hip/hip_bf16.h>
#include <stdint.h>

#define S_LEN 4096
#define HN    32
#define SSD   64
#define KD    2048      // D_IN = H*SS = D_OUT
#define MROWS 16384     // B*S

typedef __attribute__((ext_vector_type(4))) float f32x4;
typedef __attribute__((ext_vector_type(8))) short bf16x8;
typedef __attribute__((ext_vector_type(2))) int i32x2;
typedef __attribute__((ext_vector_type(4))) int i32x4;
typedef __attribute__((ext_vector_type(2))) _Float16 f16x2;
typedef __attribute__((address_space(3))) char as3char;
typedef __attribute__((address_space(1))) char as1char;

__device__ __forceinline__ unsigned short f2bf(float f){
  unsigned int u = __float_as_uint(f);
  u += 0x7FFFu + ((u >> 16) & 1u);   // round-to-nearest-even
  return (unsigned short)(u >> 16);
}

__device__ __forceinline__ f16x2 bc_h2(int v){
  union { int i; f16x2 h; } u; u.i = v; return u.h;
}

// ---------------- convert f32 -> bf16 (vectorized, 4 elts/thread) ----------------
__global__ __launch_bounds__(256) void cvt_bf16_k(const float* __restrict__ src,
                                                  unsigned short* __restrict__ dst){
  int i = (blockIdx.x * 256 + threadIdx.x) * 4;
  float4 v = *(const float4*)(src + i);
  ushort4 r;
  r.x = f2bf(v.x); r.y = f2bf(v.y); r.z = f2bf(v.z); r.w = f2bf(v.w);
  *(ushort4*)(dst + i) = r;
}

// ---------------- GEMM (bf16, global_load_lds), optional bias epilogue ----------------
__global__ __launch_bounds__(256) void gemm_bf16_k(const unsigned short* __restrict__ A,
                                                   const unsigned short* __restrict__ Bw,
                                                   const float* __restrict__ bias,  // may be null
                                                   float* __restrict__ C){
  __shared__ short As[128*32];
  __shared__ short Bs[128*32];
  const int tid  = threadIdx.x;
  const int bn   = blockIdx.x & 15;
  const int bm   = blockIdx.x >> 4;
  const int lane = tid & 63;
  const int wv   = tid >> 6;
  const int wvU  = __builtin_amdgcn_readfirstlane(wv);
  const int wm   = (wv >> 1) * 64;
  const int wn   = (wv & 1) * 64;

  f32x4 acc[4][4];
#pragma unroll
  for (int i=0;i<4;i++)
#pragma unroll
    for (int j=0;j<4;j++)
#pragma unroll
      for (int q=0;q<4;q++) acc[i][j][q] = 0.0f;

  as3char* asB = (as3char*)As;
  as3char* bsB = (as3char*)Bs;
  as1char* aG  = (as1char*)A;
  as1char* bG  = (as1char*)Bw;

  const int fr  = lane & 15;
  const int fko = (lane >> 4) * 8;

  for (int kt=0; kt<KD/32; ++kt){
    __syncthreads();                 // previous tile's frag reads done
#pragma unroll
    for (int c=0;c<2;c++){
      const int off  = (wvU*2 + c)*1024 + lane*16;
      const int row  = off >> 6;
      const int colB = off & 63;
      __builtin_amdgcn_global_load_lds(
        (__attribute__((address_space(1))) void*)(aG + (size_t)(bm*128 + row)*4096 + (size_t)kt*64 + colB),
        (__attribute__((address_space(3))) void*)(asB + (wvU*2 + c)*1024),
        16, 0, 0);
      __builtin_amdgcn_global_load_lds(
        (__attribute__((address_space(1))) void*)(bG + (size_t)(bn*128 + row)*4096 + (size_t)kt*64 + colB),
        (__attribute__((address_space(3))) void*)(bsB + (wvU*2 + c)*1024),
        16, 0, 0);
    }
    __syncthreads();                 // loads landed (vmcnt drain at barrier)

    bf16x8 af[4], bq[4];
#pragma unroll
    for (int mt=0; mt<4; mt++) af[mt] = *(const bf16x8*)&As[(wm + mt*16 + fr)*32 + fko];
#pragma unroll
    for (int nt=0; nt<4; nt++) bq[nt] = *(const bf16x8*)&Bs[(wn + nt*16 + fr)*32 + fko];
#pragma unroll
    for (int mt=0; mt<4; mt++)
#pragma unroll
      for (int nt=0; nt<4; nt++)
        acc[mt][nt] = __builtin_amdgcn_mfma_f32_16x16x32_bf16(af[mt], bq[nt], acc[mt][nt], 0, 0, 0);
  }

  float bv[4] = {0.f, 0.f, 0.f, 0.f};
  if (bias){
#pragma unroll
    for (int nt=0; nt<4; nt++) bv[nt] = bias[bn*128 + wn + nt*16 + fr];
  }
#pragma unroll
  for (int mt=0; mt<4; mt++)
#pragma unroll
    for (int nt=0; nt<4; nt++){
      const int col = bn*128 + wn + nt*16 + fr;
#pragma unroll
      for (int q=0; q<4; q++){
        const int row = bm*128 + wm + mt*16 + (lane>>4)*4 + q;
        C[(size_t)row*KD + col] = acc[mt][nt][q] + bv[nt];
      }
    }
}

// ---------------- scan: y_t = tanh(W_h y_{t-1} + hx_t) ----------------
// ONE wave per (b,h) chain (128 blocks, full chain parallelism restored).
// R14 measurement: v_readlane ~9.6 cyc issue; the 32 readlanes were ~310 of
// R12's 490 cyc/step. This version replaces readlane broadcast with LDS
// UNIFORM-ADDRESS broadcast: y kept as 64 f16 in a double-buffered LDS row;
// per step 8x ds_read_b128 at a wave-uniform address (broadcast, conflict-
// free, ~4cyc issue) deliver 32 f16 pairs feeding 32 v_dot2_f32_f16.
// Writes: 1 ds_write_b16/lane (2-way alias = free). No readlane, no DPP.
// Weights stay as 32 asm-pinned named f16x2 regs.
__global__ __attribute__((amdgpu_flat_work_group_size(64, 64)))
__attribute__((amdgpu_waves_per_eu(1, 1)))
void scan_k(const float* __restrict__ hx,
            const float* __restrict__ sw,   // [32][64][64]
            const float* __restrict__ st0,  // [4][32][64]
            unsigned short* __restrict__ ybf){ // [MROWS][2048] bf16
  const int b = blockIdx.x >> 5, h = blockIdx.x & 31;
  const int lane = threadIdx.x;        // = output index o
  const f32x4* wv = (const f32x4*)(sw + ((size_t)(h*64 + lane))*64);

  // pack W row into 32 named f16x2 (pairs (2k,2k+1))
#define MKP(Q, PA, PB) { f32x4 q_ = wv[Q]; \
    PA = f16x2{(_Float16)q_[0], (_Float16)q_[1]}; \
    PB = f16x2{(_Float16)q_[2], (_Float16)q_[3]}; }
  f16x2 p0,p1,p2,p3,p4,p5,p6,p7,p8,p9,p10,p11,p12,p13,p14,p15,
        p16,p17,p18,p19,p20,p21,p22,p23,p24,p25,p26,p27,p28,p29,p30,p31;
  MKP(0,p0,p1)   MKP(1,p2,p3)   MKP(2,p4,p5)   MKP(3,p6,p7)
  MKP(4,p8,p9)   MKP(5,p10,p11) MKP(6,p12,p13) MKP(7,p14,p15)
  MKP(8,p16,p17) MKP(9,p18,p19) MKP(10,p20,p21)MKP(11,p22,p23)
  MKP(12,p24,p25)MKP(13,p26,p27)MKP(14,p28,p29)MKP(15,p30,p31)
#undef MKP
  asm volatile("" : "+v"(p0),"+v"(p1),"+v"(p2),"+v"(p3),"+v"(p4),"+v"(p5),
                    "+v"(p6),"+v"(p7),"+v"(p8),"+v"(p9),"+v"(p10),"+v"(p11),
                    "+v"(p12),"+v"(p13),"+v"(p14),"+v"(p15));
  asm volatile("" : "+v"(p16),"+v"(p17),"+v"(p18),"+v"(p19),"+v"(p20),"+v"(p21),
                    "+v"(p22),"+v"(p23),"+v"(p24),"+v"(p25),"+v"(p26),"+v"(p27),
                    "+v"(p28),"+v"(p29),"+v"(p30),"+v"(p31));

  __shared__ __align__(16) unsigned short yf16[2][64];   // f16 recurrence buffer
  __shared__ __align__(16) unsigned short ybuf[4][64];   // bf16 global staging

  float y = st0[(b*32 + h)*64 + lane];
  yf16[0][lane] = (unsigned short)__builtin_bit_cast(unsigned short, (_Float16)y);

  const float* hxp = hx + (size_t)b*S_LEN*KD + h*64 + lane;
  unsigned short* const ybase = ybf + (size_t)b*S_LEN*KD + h*64;  // chain base
  const int srow = lane >> 4;          // drain: buffered row (0..3)
  const int scol = (lane & 15) << 2;   // drain: 4-ushort (8B) chunk in row

  // named prefetch registers (loads-only global queue)
  float h0 = hxp[0*(size_t)KD], h1 = hxp[1*(size_t)KD],
        h2 = hxp[2*(size_t)KD], h3 = hxp[3*(size_t)KD];

// 4 dot2 from one i32x4 broadcast (pairs 4k..4k+3)
#define DOT4(R, PA,PB,PC,PD) \
    a0 = __builtin_amdgcn_fdot2(PA, bc_h2(R[0]), a0, false); \
    a1 = __builtin_amdgcn_fdot2(PB, bc_h2(R[1]), a1, false); \
    a2 = __builtin_amdgcn_fdot2(PC, bc_h2(R[2]), a2, false); \
    a3 = __builtin_amdgcn_fdot2(PD, bc_h2(R[3]), a3, false);

#define RNN_STEP(H, J, TT, CUR, NXT) { \
    const float hxv = H; \
    { const int tn_ = ((TT) + 4 < S_LEN) ? ((TT) + 4) : (S_LEN - 1); \
      H = hxp[(size_t)tn_ * KD]; } \
    const i32x4* yb4 = (const i32x4*)yf16[CUR];   /* wave-uniform addr */ \
    const i32x4 r0 = yb4[0], r1 = yb4[1], r2 = yb4[2], r3 = yb4[3]; \
    const i32x4 r4 = yb4[4], r5 = yb4[5], r6 = yb4[6], r7 = yb4[7]; \
    float a0=0.f, a1=0.f, a2=0.f, a3=0.f; \
    DOT4(r0, p0,p1,p2,p3)     DOT4(r1, p4,p5,p6,p7) \
    DOT4(r2, p8,p9,p10,p11)   DOT4(r3, p12,p13,p14,p15) \
    DOT4(r4, p16,p17,p18,p19) DOT4(r5, p20,p21,p22,p23) \
    DOT4(r6, p24,p25,p26,p27) DOT4(r7, p28,p29,p30,p31) \
    const float u = (a0 + a1) + (a2 + a3) + hxv; \
    const float e = __expf(2.0f*u); \
    y = 1.0f - 2.0f*__builtin_amdgcn_rcpf(e + 1.0f); \
    yf16[NXT][lane] = (unsigned short)__builtin_bit_cast(unsigned short, (_Float16)y); \
    ybuf[J][lane] = f2bf(y); }

  for (int t = 0; t < S_LEN; t += 4){
    RNN_STEP(h0, 0, t+0, 0, 1)
    RNN_STEP(h1, 1, t+1, 1, 0)
    RNN_STEP(h2, 2, t+2, 0, 1)
    RNN_STEP(h3, 3, t+3, 1, 0)
    // drain the 4-step tile: one 8B store per lane (rows t..t+3)
    const i32x2 v = *(const i32x2*)&ybuf[srow][scol];
    *(i32x2*)(ybase + (size_t)(t + srow)*KD + scol) = v;
  }
#undef RNN_STEP
#undef DOT4
}

extern "C" void kernel_launch(void* const* d_in, const int* in_sizes, int n_in,
                              void* d_out, int out_size, void* d_ws, size_t ws_size,
                              hipStream_t stream) {
  const float* x      = (const float*)d_in[0];
  const float* st0    = (const float*)d_in[1];
  const float* w_in   = (const float*)d_in[2];
  const float* w_st   = (const float*)d_in[3];
  const float* b_st   = (const float*)d_in[4];
  const float* w_out  = (const float*)d_in[5];
  float* out = (float*)d_out;

  const size_t HX_B = (size_t)MROWS * KD * 4;       // 134217728
  const size_t Y_B  = (size_t)MROWS * KD * 2;       // 67108864
  const size_t WO_B = (size_t)KD * KD * 2;          // 8388608
  if (ws_size < HX_B + Y_B + WO_B) return;          // fail loudly rather than corrupt
  char* ws = (char*)d_ws;
  float*          hx   = (float*)ws;
  unsigned short* ybf  = (unsigned short*)(ws + HX_B);   // doubles as x_bf16
  unsigned short* wbf  = (unsigned short*)(ws + HX_B + Y_B); // w_in then w_out

  // phase 1: convert x and w_in, input GEMM (+bias)
  cvt_bf16_k<<<dim3((MROWS*(size_t)KD)/1024), dim3(256), 0, stream>>>(x, ybf);
  cvt_bf16_k<<<dim3((KD*KD)/1024), dim3(256), 0, stream>>>(w_in, wbf);
  gemm_bf16_k<<<dim3((MROWS/128)*(KD/128)), dim3(256), 0, stream>>>(ybf, wbf, b_st, hx);
  // phase 2: scan (overwrites x_bf16 region with y), then output GEMM
  scan_k<<<dim3(128), dim3(64), 0, stream>>>(hx, w_st, st0, ybf);
  cvt_bf16_k<<<dim3((KD*KD)/1024), dim3(256), 0, stream>>>(w_out, wbf);
  gemm_bf16_k<<<dim3((MROWS/128)*(KD/128)), dim3(256), 0, stream>>>(ybf, wbf, nullptr, out);
}